// Round 6
// baseline (300.482 us; speedup 1.0000x reference)
//
#include <hip/hip_runtime.h>
#include <hip/hip_bf16.h>
#include <cstdint>

// ---------------------------------------------------------------------------
// N=50000, E=600000, D_IN=256, H1=128, H2=64, DK=64, HEADS=2 (dk=32).
// R6: SpMM = 2 waves per ROW (feature-split, 64 features/wave, 1/lane),
// 4-deep gather batches -> 100k independent waves. Reverts R5's 2-rows/wave
// interleave. CSR scan merge + prep/kv merge retained from R5.
// ---------------------------------------------------------------------------

typedef __attribute__((ext_vector_type(8))) short short8;
typedef __attribute__((ext_vector_type(4))) float f32x4;
typedef __attribute__((ext_vector_type(4))) unsigned short ushort4_t;

__device__ __forceinline__ unsigned short f2bf(float f) {
    unsigned int u = __builtin_bit_cast(unsigned int, f);
    u += 0x7fffu + ((u >> 16) & 1u);   // RNE
    return (unsigned short)(u >> 16);
}
__device__ __forceinline__ float bf2f(unsigned short v) {
    return __builtin_bit_cast(float, (unsigned int)v << 16);
}

// ---------------- CSR build --------------------------------------------------

__global__ void hist_kernel(const int* __restrict__ rows, int* __restrict__ cnt, int E) {
    int i = blockIdx.x * blockDim.x + threadIdx.x;
    if (i < E) atomicAdd(&cnt[rows[i]], 1);
}

__global__ void scan1_kernel(const int* __restrict__ cnt, int* __restrict__ excl,
                             int* __restrict__ bsum, int N) {
    __shared__ int sh[256];
    int t = threadIdx.x;
    int i = blockIdx.x * 256 + t;
    int v = (i < N) ? cnt[i] : 0;
    sh[t] = v;
    __syncthreads();
    for (int off = 1; off < 256; off <<= 1) {
        int x = (t >= off) ? sh[t - off] : 0;
        __syncthreads();
        sh[t] += x;
        __syncthreads();
    }
    if (i < N) excl[i] = sh[t] - v;
    if (t == 255) bsum[blockIdx.x] = sh[255];
}

// scan2 folded in: every block locally scans bsum[0..nb) to get its offset.
__global__ void scan23_kernel(const int* __restrict__ excl, const int* __restrict__ bsum,
                              int* __restrict__ row_start, int* __restrict__ cursor,
                              int nb, int N, int E) {
    __shared__ int sh[256];
    int t = threadIdx.x;
    int v = (t < nb) ? bsum[t] : 0;
    sh[t] = v;
    __syncthreads();
    for (int off = 1; off < 256; off <<= 1) {
        int x = (t >= off) ? sh[t - off] : 0;
        __syncthreads();
        sh[t] += x;
        __syncthreads();
    }
    int boff = (blockIdx.x > 0) ? sh[blockIdx.x - 1] : 0;
    int i = blockIdx.x * 256 + t;
    if (i < N) {
        int w = excl[i] + boff;
        row_start[i] = w;
        cursor[i] = w;
    }
    if (i == 0) row_start[N] = E;
}

__global__ void scatter_kernel(const int* __restrict__ rows, const int* __restrict__ colsIn,
                               const float* __restrict__ valsIn, int* __restrict__ cursor,
                               int2* __restrict__ pack, int E) {
    int i = blockIdx.x * blockDim.x + threadIdx.x;
    if (i < E) {
        int r = rows[i];
        int p = atomicAdd(&cursor[r], 1);
        pack[p] = make_int2(colsIn[i], __float_as_int(valsIn[i]));
    }
}

// ---------------- weight prep + K/V projection (merged) ---------------------

__global__ __launch_bounds__(256) void prep_kv_kernel(
    const float* __restrict__ Wh, const float* __restrict__ Wq,
    const float* __restrict__ Wo, const float* __restrict__ Wmu,
    const float* __restrict__ Wvar, const float* __restrict__ cond,
    const float* __restrict__ Wk, const float* __restrict__ Wv,
    unsigned short* __restrict__ WhT, unsigned short* __restrict__ WqT,
    unsigned short* __restrict__ WoT, unsigned short* __restrict__ WmuT,
    unsigned short* __restrict__ WvarT, unsigned short* __restrict__ Ktt,
    unsigned short* __restrict__ Vt)
{
    const int t = threadIdx.x;
    if (blockIdx.x < 256) {
        int idx = blockIdx.x * 256 + t;
        if (idx < 32768) {
            int n = idx & 127, k = idx >> 7;                 // k<256
            WhT[n * 256 + k] = f2bf(Wh[k * 128 + n]);
        } else if (idx < 40960) {
            int i = idx - 32768, n = i & 63, k = i >> 6;     // k<128
            WqT[n * 128 + k] = f2bf(Wq[k * 64 + n]);
        } else if (idx < 49152) {
            int i = idx - 40960, n = i & 127, k = i >> 7;    // k<64
            WoT[n * 64 + k] = f2bf(Wo[k * 128 + n]);
        } else if (idx < 57344) {
            int i = idx - 49152, n = i & 63, k = i >> 6;
            WmuT[n * 128 + k] = f2bf(Wmu[k * 64 + n]);
        } else if (idx < 65536) {
            int i = idx - 57344, n = i & 63, k = i >> 6;
            WvarT[n * 128 + k] = f2bf(Wvar[k * 64 + n]);
        }
    } else {
        int b2 = blockIdx.x - 256;           // 0..63, 2 keys per block
        __shared__ float c[2][128];
        c[t >> 7][t & 127] = cond[b2 * 256 + t];
        __syncthreads();
        int j = b2 * 2 + (t >> 7);           // key index
        int tl = t & 127;
        const float* W = (tl < 64) ? Wk : Wv;
        int col = tl & 63;
        float acc = 0.f;
#pragma unroll 8
        for (int k = 0; k < 128; ++k) acc = fmaf(c[t >> 7][k], W[k * 64 + col], acc);
        int h = col >> 5, d = col & 31;
        if (tl < 64) Ktt[((size_t)h * 128 + j) * 32 + d] = f2bf(acc * 0.17677669529663687f);
        else         Vt[((size_t)h * 32 + d) * 128 + j] = f2bf(acc);
    }
}

// ---------------- GCN1 GEMM: support1 = lrelu(ns_emb @ Wh) ------------------

__global__ __launch_bounds__(256) void gcn1_gemm(
    const float* __restrict__ A, const unsigned short* __restrict__ BT,
    unsigned short* __restrict__ C, int M)
{
    __shared__ unsigned short As[128][72];
    __shared__ unsigned short Bs[128][72];

    const int tid = threadIdx.x;
    const int lane = tid & 63, wave = tid >> 6;
    const int wm = wave & 1, wn = wave >> 1;
    const int quad = lane >> 4, l16 = lane & 15;
    const int r0 = blockIdx.x * 128;

    f32x4 acc[4][4];
#pragma unroll
    for (int mt = 0; mt < 4; ++mt)
#pragma unroll
        for (int nt = 0; nt < 4; ++nt)
#pragma unroll
            for (int r = 0; r < 4; ++r) acc[mt][nt][r] = 0.f;

    for (int kc = 0; kc < 256; kc += 64) {
#pragma unroll
        for (int i = 0; i < 8; ++i) {
            int f = tid + 256 * i;
            int row = f >> 4, kq = (f & 15) << 2;
            int gr = r0 + row;
            if (gr >= M) gr = M - 1;
            float4 v = *reinterpret_cast<const float4*>(&A[(size_t)gr * 256 + kc + kq]);
            ushort4_t pv;
            pv[0] = f2bf(v.x); pv[1] = f2bf(v.y); pv[2] = f2bf(v.z); pv[3] = f2bf(v.w);
            *reinterpret_cast<ushort4_t*>(&As[row][kq]) = pv;
        }
#pragma unroll
        for (int i = 0; i < 4; ++i) {
            int f = tid + 256 * i;
            int n = f >> 3, k8 = (f & 7) << 3;
            *reinterpret_cast<short8*>(&Bs[n][k8]) =
                *reinterpret_cast<const short8*>(&BT[(size_t)n * 256 + kc + k8]);
        }
        __syncthreads();

#pragma unroll
        for (int ks = 0; ks < 2; ++ks) {
            const int koff = ks * 32 + quad * 8;
            short8 a[4], b[4];
#pragma unroll
            for (int mt = 0; mt < 4; ++mt)
                a[mt] = *reinterpret_cast<const short8*>(&As[wm * 64 + mt * 16 + l16][koff]);
#pragma unroll
            for (int nt = 0; nt < 4; ++nt)
                b[nt] = *reinterpret_cast<const short8*>(&Bs[wn * 64 + nt * 16 + l16][koff]);
#pragma unroll
            for (int mt = 0; mt < 4; ++mt)
#pragma unroll
                for (int nt = 0; nt < 4; ++nt)
                    acc[mt][nt] = __builtin_amdgcn_mfma_f32_16x16x32_bf16(
                        a[mt], b[nt], acc[mt][nt], 0, 0, 0);
        }
        __syncthreads();
    }

#pragma unroll
    for (int mt = 0; mt < 4; ++mt)
#pragma unroll
        for (int nt = 0; nt < 4; ++nt) {
            int gc = wn * 64 + nt * 16 + l16;
#pragma unroll
            for (int r = 0; r < 4; ++r) {
                int gr = r0 + wm * 64 + mt * 16 + quad * 4 + r;
                if (gr < M) {
                    float v = acc[mt][nt][r];
                    v = v > 0.f ? v : 0.01f * v;
                    C[(size_t)gr * 128 + gc] = f2bf(v);
                }
            }
        }
}

// ---------------- fused attention + muvar kernel ----------------------------

__global__ __launch_bounds__(256) void attn_muvar_kernel(
    const unsigned short* __restrict__ hidden,  // [N,128] bf16
    const unsigned short* __restrict__ WqT,     // [64][128] bf16
    const unsigned short* __restrict__ Ktt,     // [2][128][32] bf16 (scaled)
    const unsigned short* __restrict__ Vt,      // [2][32][128] bf16
    const unsigned short* __restrict__ WoT,     // [128][64] bf16
    const unsigned short* __restrict__ WmuT,    // [64][128] bf16
    const unsigned short* __restrict__ WvarT,   // [64][128] bf16
    unsigned short* __restrict__ muvar,         // [N,128] bf16
    int M)
{
    __shared__ unsigned short Ap[128 * 136];
    __shared__ unsigned short Bp[10240];
    __shared__ unsigned short Cp[128 * 72];
    __shared__ float redm[2][128];
    __shared__ float reds[2][128];

    const int tid = threadIdx.x;
    const int lane = tid & 63, wave = tid >> 6;
    const int wm = wave & 1, wn = wave >> 1;
    const int quad = lane >> 4, l16 = lane & 15;
    const int r0 = blockIdx.x * 128;

#pragma unroll
    for (int i = 0; i < 8; ++i) {
        int f = tid + 256 * i;
        int row = f >> 4, k8 = (f & 15) << 3;
        int gr = r0 + row;
        if (gr >= M) gr = M - 1;
        *reinterpret_cast<short8*>(&Ap[row * 136 + k8]) =
            *reinterpret_cast<const short8*>(&hidden[(size_t)gr * 128 + k8]);
    }
#pragma unroll
    for (int i = 0; i < 4; ++i) {
        int f = tid + 256 * i;
        int n = f >> 4, k8 = (f & 15) << 3;
        *reinterpret_cast<short8*>(&Bp[n * 136 + k8]) =
            *reinterpret_cast<const short8*>(&WqT[(size_t)n * 128 + k8]);
    }
    __syncthreads();

    // Q = hidden @ Wq -> Cp
    {
        f32x4 accq[4][2];
#pragma unroll
        for (int mt = 0; mt < 4; ++mt)
#pragma unroll
            for (int nt = 0; nt < 2; ++nt)
#pragma unroll
                for (int r = 0; r < 4; ++r) accq[mt][nt][r] = 0.f;
#pragma unroll
        for (int ks = 0; ks < 4; ++ks) {
            const int koff = ks * 32 + quad * 8;
            short8 a[4], b[2];
#pragma unroll
            for (int mt = 0; mt < 4; ++mt)
                a[mt] = *reinterpret_cast<const short8*>(&Ap[(wm * 64 + mt * 16 + l16) * 136 + koff]);
#pragma unroll
            for (int nt = 0; nt < 2; ++nt)
                b[nt] = *reinterpret_cast<const short8*>(&Bp[(wn * 32 + nt * 16 + l16) * 136 + koff]);
#pragma unroll
            for (int mt = 0; mt < 4; ++mt)
#pragma unroll
                for (int nt = 0; nt < 2; ++nt)
                    accq[mt][nt] = __builtin_amdgcn_mfma_f32_16x16x32_bf16(
                        a[mt], b[nt], accq[mt][nt], 0, 0, 0);
        }
#pragma unroll
        for (int mt = 0; mt < 4; ++mt)
#pragma unroll
            for (int nt = 0; nt < 2; ++nt) {
                int col = wn * 32 + nt * 16 + l16;
#pragma unroll
                for (int r = 0; r < 4; ++r) {
                    int row = wm * 64 + mt * 16 + quad * 4 + r;
                    Cp[row * 72 + col] = f2bf(accq[mt][nt][r]);
                }
            }
    }
    __syncthreads();

    for (int h = 0; h < 2; ++h) {
#pragma unroll
        for (int i = 0; i < 2; ++i) {
            int f = tid + 256 * i;
            int key = f >> 2, d8 = (f & 3) << 3;
            *reinterpret_cast<short8*>(&Bp[key * 40 + d8]) =
                *reinterpret_cast<const short8*>(&Ktt[((size_t)h * 128 + key) * 32 + d8]);
        }
#pragma unroll
        for (int i = 0; i < 2; ++i) {
            int f = tid + 256 * i;
            int d = f >> 4, k8 = (f & 15) << 3;
            *reinterpret_cast<short8*>(&Bp[5120 + d * 136 + k8]) =
                *reinterpret_cast<const short8*>(&Vt[((size_t)h * 32 + d) * 128 + k8]);
        }
        __syncthreads();

        f32x4 accl[4][4];
        {
            short8 a[4], b[4];
#pragma unroll
            for (int mt = 0; mt < 4; ++mt)
                a[mt] = *reinterpret_cast<const short8*>(&Cp[(wm * 64 + mt * 16 + l16) * 72 + h * 32 + quad * 8]);
#pragma unroll
            for (int nt = 0; nt < 4; ++nt)
                b[nt] = *reinterpret_cast<const short8*>(&Bp[(wn * 64 + nt * 16 + l16) * 40 + quad * 8]);
#pragma unroll
            for (int mt = 0; mt < 4; ++mt)
#pragma unroll
                for (int nt = 0; nt < 4; ++nt) {
                    f32x4 z; z[0] = 0.f; z[1] = 0.f; z[2] = 0.f; z[3] = 0.f;
                    accl[mt][nt] = __builtin_amdgcn_mfma_f32_16x16x32_bf16(a[mt], b[nt], z, 0, 0, 0);
                }
        }

#pragma unroll
        for (int mt = 0; mt < 4; ++mt)
#pragma unroll
            for (int r = 0; r < 4; ++r) {
                float mx = fmaxf(fmaxf(accl[mt][0][r], accl[mt][1][r]),
                                 fmaxf(accl[mt][2][r], accl[mt][3][r]));
#pragma unroll
                for (int off = 1; off < 16; off <<= 1)
                    mx = fmaxf(mx, __shfl_xor(mx, off, 64));
                if (l16 == 0) redm[wn][wm * 64 + mt * 16 + quad * 4 + r] = mx;
            }
        __syncthreads();
#pragma unroll
        for (int mt = 0; mt < 4; ++mt)
#pragma unroll
            for (int r = 0; r < 4; ++r) {
                int lr = wm * 64 + mt * 16 + quad * 4 + r;
                float fm = fmaxf(redm[0][lr], redm[1][lr]);
                float s = 0.f;
#pragma unroll
                for (int nt = 0; nt < 4; ++nt) {
                    float e = __expf(accl[mt][nt][r] - fm);
                    accl[mt][nt][r] = e;
                    s += e;
                }
#pragma unroll
                for (int off = 1; off < 16; off <<= 1)
                    s += __shfl_xor(s, off, 64);
                if (l16 == 0) reds[wn][lr] = s;
            }
        __syncthreads();
#pragma unroll
        for (int mt = 0; mt < 4; ++mt)
#pragma unroll
            for (int r = 0; r < 4; ++r) {
                int lr = wm * 64 + mt * 16 + quad * 4 + r;
                float inv = 1.0f / (reds[0][lr] + reds[1][lr]);
#pragma unroll
                for (int nt = 0; nt < 4; ++nt)
                    Ap[lr * 136 + wn * 64 + nt * 16 + l16] = f2bf(accl[mt][nt][r] * inv);
            }
        __syncthreads();

        {
            f32x4 accc[4];
#pragma unroll
            for (int mt = 0; mt < 4; ++mt)
#pragma unroll
                for (int r = 0; r < 4; ++r) accc[mt][r] = 0.f;
#pragma unroll
            for (int ks = 0; ks < 4; ++ks) {
                const int koff = ks * 32 + quad * 8;
                short8 a[4];
#pragma unroll
                for (int mt = 0; mt < 4; ++mt)
                    a[mt] = *reinterpret_cast<const short8*>(&Ap[(wm * 64 + mt * 16 + l16) * 136 + koff]);
                short8 bb = *reinterpret_cast<const short8*>(&Bp[5120 + (wn * 16 + l16) * 136 + koff]);
#pragma unroll
                for (int mt = 0; mt < 4; ++mt)
                    accc[mt] = __builtin_amdgcn_mfma_f32_16x16x32_bf16(a[mt], bb, accc[mt], 0, 0, 0);
            }
#pragma unroll
            for (int mt = 0; mt < 4; ++mt)
#pragma unroll
                for (int r = 0; r < 4; ++r) {
                    int row = wm * 64 + mt * 16 + quad * 4 + r;
                    Cp[row * 72 + h * 32 + wn * 16 + l16] = f2bf(accc[mt][r]);
                }
        }
        __syncthreads();
    }

    // attended = ctx @ Wo -> Ap
#pragma unroll
    for (int i = 0; i < 4; ++i) {
        int f = tid + 256 * i;
        int n = f >> 3, k8 = (f & 7) << 3;
        *reinterpret_cast<short8*>(&Bp[n * 72 + k8]) =
            *reinterpret_cast<const short8*>(&WoT[(size_t)n * 64 + k8]);
    }
    __syncthreads();
    {
        f32x4 acca[4][4];
#pragma unroll
        for (int mt = 0; mt < 4; ++mt)
#pragma unroll
            for (int nt = 0; nt < 4; ++nt)
#pragma unroll
                for (int r = 0; r < 4; ++r) acca[mt][nt][r] = 0.f;
#pragma unroll
        for (int ks = 0; ks < 2; ++ks) {
            const int koff = ks * 32 + quad * 8;
            short8 a[4], b[4];
#pragma unroll
            for (int mt = 0; mt < 4; ++mt)
                a[mt] = *reinterpret_cast<const short8*>(&Cp[(wm * 64 + mt * 16 + l16) * 72 + koff]);
#pragma unroll
            for (int nt = 0; nt < 4; ++nt)
                b[nt] = *reinterpret_cast<const short8*>(&Bp[(wn * 64 + nt * 16 + l16) * 72 + koff]);
#pragma unroll
            for (int mt = 0; mt < 4; ++mt)
#pragma unroll
                for (int nt = 0; nt < 4; ++nt)
                    acca[mt][nt] = __builtin_amdgcn_mfma_f32_16x16x32_bf16(
                        a[mt], b[nt], acca[mt][nt], 0, 0, 0);
        }
#pragma unroll
        for (int mt = 0; mt < 4; ++mt)
#pragma unroll
            for (int nt = 0; nt < 4; ++nt) {
                int col = wn * 64 + nt * 16 + l16;
#pragma unroll
                for (int r = 0; r < 4; ++r) {
                    int row = wm * 64 + mt * 16 + quad * 4 + r;
                    Ap[row * 136 + col] = f2bf(acca[mt][nt][r]);
                }
            }
    }
    __syncthreads();

    for (int half = 0; half < 2; ++half) {
        const unsigned short* WT = half ? WvarT : WmuT;
#pragma unroll
        for (int i = 0; i < 4; ++i) {
            int f = tid + 256 * i;
            int n = f >> 4, k8 = (f & 15) << 3;
            *reinterpret_cast<short8*>(&Bp[n * 136 + k8]) =
                *reinterpret_cast<const short8*>(&WT[(size_t)n * 128 + k8]);
        }
        __syncthreads();
        f32x4 accm[4][2];
#pragma unroll
        for (int mt = 0; mt < 4; ++mt)
#pragma unroll
            for (int nt = 0; nt < 2; ++nt)
#pragma unroll
                for (int r = 0; r < 4; ++r) accm[mt][nt][r] = 0.f;
#pragma unroll
        for (int ks = 0; ks < 4; ++ks) {
            const int koff = ks * 32 + quad * 8;
            short8 a[4], b[2];
#pragma unroll
            for (int mt = 0; mt < 4; ++mt)
                a[mt] = *reinterpret_cast<const short8*>(&Ap[(wm * 64 + mt * 16 + l16) * 136 + koff]);
#pragma unroll
            for (int nt = 0; nt < 2; ++nt)
                b[nt] = *reinterpret_cast<const short8*>(&Bp[(wn * 32 + nt * 16 + l16) * 136 + koff]);
#pragma unroll
            for (int mt = 0; mt < 4; ++mt)
#pragma unroll
                for (int nt = 0; nt < 2; ++nt)
                    accm[mt][nt] = __builtin_amdgcn_mfma_f32_16x16x32_bf16(
                        a[mt], b[nt], accm[mt][nt], 0, 0, 0);
        }
#pragma unroll
        for (int mt = 0; mt < 4; ++mt)
#pragma unroll
            for (int nt = 0; nt < 2; ++nt) {
                int gc = half * 64 + wn * 32 + nt * 16 + l16;
#pragma unroll
                for (int r = 0; r < 4; ++r) {
                    int gr = r0 + wm * 64 + mt * 16 + quad * 4 + r;
                    if (gr < M) {
                        float v = accm[mt][nt][r];
                        v = v > 0.f ? v : 0.01f * v;
                        muvar[(size_t)gr * 128 + gc] = f2bf(v);
                    }
                }
            }
        __syncthreads();
    }
}

// ---------------- SpMM: 2 waves per row (feature-split), 4-deep batches -----
// Wave covers 64 features (1 ushort/lane). gwave = row*2 + half.
// pack = (col, valbits); pack loads are wave-uniform (scalar path).

template<bool SPLIT, typename OT>
__global__ __launch_bounds__(256) void spmm_kernel(
    const int* __restrict__ row_start, const int2* __restrict__ pack,
    const unsigned short* __restrict__ X,
    OT* __restrict__ out0, OT* __restrict__ out1, int N)
{
    const int wave = threadIdx.x >> 6, lane = threadIdx.x & 63;
    const int gwave = blockIdx.x * 4 + wave;
    const int r = gwave >> 1;
    const int half = gwave & 1;
    if (r >= N) return;
    int s = __builtin_amdgcn_readfirstlane(row_start[r]);
    int e = __builtin_amdgcn_readfirstlane(row_start[r + 1]);
    const int fo = half * 64 + lane;

    float a0 = 0.f, a1 = 0.f, a2 = 0.f, a3 = 0.f;
    int i = s;
    for (; i + 4 <= e; i += 4) {
        int2 p0 = pack[i], p1 = pack[i + 1], p2 = pack[i + 2], p3 = pack[i + 3];
        unsigned short x0 = X[(size_t)p0.x * 128 + fo];
        unsigned short x1 = X[(size_t)p1.x * 128 + fo];
        unsigned short x2 = X[(size_t)p2.x * 128 + fo];
        unsigned short x3 = X[(size_t)p3.x * 128 + fo];
        a0 = fmaf(__int_as_float(p0.y), bf2f(x0), a0);
        a1 = fmaf(__int_as_float(p1.y), bf2f(x1), a1);
        a2 = fmaf(__int_as_float(p2.y), bf2f(x2), a2);
        a3 = fmaf(__int_as_float(p3.y), bf2f(x3), a3);
    }
    for (; i < e; ++i) {
        int2 p0 = pack[i];
        unsigned short x0 = X[(size_t)p0.x * 128 + fo];
        a0 = fmaf(__int_as_float(p0.y), bf2f(x0), a0);
    }
    float o = (a0 + a1) + (a2 + a3);
    o = o > 0.f ? o : 0.01f * o;

    if constexpr (!SPLIT) {
        out0[(size_t)r * 128 + fo] = (OT)f2bf(o);
    } else {
        if (half == 0) out0[(size_t)r * 64 + lane] = o;   // mu
        else           out1[(size_t)r * 64 + lane] = o;   // var
    }
}

// ---------------------------------------------------------------------------

extern "C" void kernel_launch(void* const* d_in, const int* in_sizes, int n_in,
                              void* d_out, int out_size, void* d_ws, size_t ws_size,
                              hipStream_t stream)
{
    const float* ns_emb   = (const float*)d_in[0];
    const int*   erows    = (const int*)d_in[1];
    const int*   ecols    = (const int*)d_in[2];
    const float* evals    = (const float*)d_in[3];
    const float* cond     = (const float*)d_in[4];
    const float* W_hidden = (const float*)d_in[5];
    const float* W_mu     = (const float*)d_in[6];
    const float* W_var    = (const float*)d_in[7];
    const float* Wq       = (const float*)d_in[8];
    const float* Wk       = (const float*)d_in[9];
    const float* Wv       = (const float*)d_in[10];
    const float* Wo       = (const float*)d_in[11];

    const int N = in_sizes[0] / 256;  // 50000
    const int E = in_sizes[1];        // 600000

    typedef unsigned short bf16;
    uint8_t* p = (uint8_t*)d_ws;
    auto alloc = [&](size_t bytes) {
        uint8_t* r = p;
        p += (bytes + 255) & ~(size_t)255;
        return r;
    };
    bf16* support1 = (bf16*)alloc(sizeof(bf16) * (size_t)N * 128);
    bf16* hidden   = (bf16*)alloc(sizeof(bf16) * (size_t)N * 128);
    bf16* muvarb   = (bf16*)alloc(sizeof(bf16) * (size_t)N * 128);
    bf16* Ktt      = (bf16*)alloc(sizeof(bf16) * 2 * 128 * 32);
    bf16* Vt       = (bf16*)alloc(sizeof(bf16) * 2 * 32 * 128);
    bf16* WhT      = (bf16*)alloc(sizeof(bf16) * 128 * 256);
    bf16* WqT      = (bf16*)alloc(sizeof(bf16) * 64 * 128);
    bf16* WoT      = (bf16*)alloc(sizeof(bf16) * 128 * 64);
    bf16* WmuT     = (bf16*)alloc(sizeof(bf16) * 64 * 128);
    bf16* WvarT    = (bf16*)alloc(sizeof(bf16) * 64 * 128);
    int*  cnt      = (int*)alloc(sizeof(int) * N);
    int*  excl     = (int*)alloc(sizeof(int) * N);
    int*  bsum     = (int*)alloc(sizeof(int) * 256);
    int*  row_start= (int*)alloc(sizeof(int) * (N + 1));
    int*  cursor   = (int*)alloc(sizeof(int) * N);
    int2* pack     = (int2*)alloc(sizeof(int2) * E);

    // ---- CSR build ----
    hipMemsetAsync(cnt, 0, sizeof(int) * N, stream);
    hist_kernel<<<(E + 255) / 256, 256, 0, stream>>>(erows, cnt, E);
    int nb = (N + 255) / 256;   // 196
    scan1_kernel<<<nb, 256, 0, stream>>>(cnt, excl, bsum, N);
    scan23_kernel<<<nb, 256, 0, stream>>>(excl, bsum, row_start, cursor, nb, N, E);
    scatter_kernel<<<(E + 255) / 256, 256, 0, stream>>>(erows, ecols, evals, cursor, pack, E);

    // ---- weight prep + K/V (merged) ----
    prep_kv_kernel<<<320, 256, 0, stream>>>(W_hidden, Wq, Wo, W_mu, W_var,
                                            cond, Wk, Wv,
                                            WhT, WqT, WoT, WmuT, WvarT, Ktt, Vt);

    const int mb = (N + 127) / 128;  // 391
    const int sblocks = (2 * N + 3) / 4;  // 2 waves per row, 4 waves/block

    // ---- GCN1 ----
    gcn1_gemm<<<mb, 256, 0, stream>>>(ns_emb, WhT, support1, N);
    spmm_kernel<false, bf16><<<sblocks, 256, 0, stream>>>(
        row_start, pack, support1, hidden, nullptr, N);

    // ---- fused attention -> muvar ----
    attn_muvar_kernel<<<mb, 256, 0, stream>>>(hidden, WqT, Ktt, Vt, WoT,
                                              WmuT, WvarT, muvarb, N);

    // ---- final SpMM (split mu/var, fp32 out) ----
    float* out = (float*)d_out;
    spmm_kernel<true, float><<<sblocks, 256, 0, stream>>>(
        row_start, pack, muvarb, out, out + (size_t)N * 64, N);
}

// Round 7
// 270.598 us; speedup vs baseline: 1.1104x; 1.1104x over previous
//
#include <hip/hip_runtime.h>
#include <hip/hip_bf16.h>
#include <cstdint>

// ---------------------------------------------------------------------------
// N=50000, E=600000, D_IN=256, H1=128, H2=64, DK=64, HEADS=2 (dk=32).
// R7: SpMM reverted to R4 shape (1 row/wave, full 256B row gather, ushort2 per
// lane) with an 8-deep gather pipeline and a clamped tail batch (no serial
// tail). R5/R6 spmm variants both regressed (recorded). Merged scans +
// prep_kv, fused attention+muvar, gcn1 MFMA GEMM retained.
// ---------------------------------------------------------------------------

typedef __attribute__((ext_vector_type(8))) short short8;
typedef __attribute__((ext_vector_type(4))) float f32x4;
typedef __attribute__((ext_vector_type(4))) unsigned short ushort4_t;

__device__ __forceinline__ unsigned short f2bf(float f) {
    unsigned int u = __builtin_bit_cast(unsigned int, f);
    u += 0x7fffu + ((u >> 16) & 1u);   // RNE
    return (unsigned short)(u >> 16);
}
__device__ __forceinline__ float bf2f(unsigned short v) {
    return __builtin_bit_cast(float, (unsigned int)v << 16);
}

// ---------------- CSR build --------------------------------------------------

__global__ void hist_kernel(const int* __restrict__ rows, int* __restrict__ cnt, int E) {
    int i = blockIdx.x * blockDim.x + threadIdx.x;
    if (i < E) atomicAdd(&cnt[rows[i]], 1);
}

__global__ void scan1_kernel(const int* __restrict__ cnt, int* __restrict__ excl,
                             int* __restrict__ bsum, int N) {
    __shared__ int sh[256];
    int t = threadIdx.x;
    int i = blockIdx.x * 256 + t;
    int v = (i < N) ? cnt[i] : 0;
    sh[t] = v;
    __syncthreads();
    for (int off = 1; off < 256; off <<= 1) {
        int x = (t >= off) ? sh[t - off] : 0;
        __syncthreads();
        sh[t] += x;
        __syncthreads();
    }
    if (i < N) excl[i] = sh[t] - v;
    if (t == 255) bsum[blockIdx.x] = sh[255];
}

// scan2 folded in: every block locally scans bsum[0..nb) to get its offset.
__global__ void scan23_kernel(const int* __restrict__ excl, const int* __restrict__ bsum,
                              int* __restrict__ row_start, int* __restrict__ cursor,
                              int nb, int N, int E) {
    __shared__ int sh[256];
    int t = threadIdx.x;
    int v = (t < nb) ? bsum[t] : 0;
    sh[t] = v;
    __syncthreads();
    for (int off = 1; off < 256; off <<= 1) {
        int x = (t >= off) ? sh[t - off] : 0;
        __syncthreads();
        sh[t] += x;
        __syncthreads();
    }
    int boff = (blockIdx.x > 0) ? sh[blockIdx.x - 1] : 0;
    int i = blockIdx.x * 256 + t;
    if (i < N) {
        int w = excl[i] + boff;
        row_start[i] = w;
        cursor[i] = w;
    }
    if (i == 0) row_start[N] = E;
}

__global__ void scatter_kernel(const int* __restrict__ rows, const int* __restrict__ colsIn,
                               const float* __restrict__ valsIn, int* __restrict__ cursor,
                               int2* __restrict__ pack, int E) {
    int i = blockIdx.x * blockDim.x + threadIdx.x;
    if (i < E) {
        int r = rows[i];
        int p = atomicAdd(&cursor[r], 1);
        pack[p] = make_int2(colsIn[i], __float_as_int(valsIn[i]));
    }
}

// ---------------- weight prep + K/V projection (merged) ---------------------

__global__ __launch_bounds__(256) void prep_kv_kernel(
    const float* __restrict__ Wh, const float* __restrict__ Wq,
    const float* __restrict__ Wo, const float* __restrict__ Wmu,
    const float* __restrict__ Wvar, const float* __restrict__ cond,
    const float* __restrict__ Wk, const float* __restrict__ Wv,
    unsigned short* __restrict__ WhT, unsigned short* __restrict__ WqT,
    unsigned short* __restrict__ WoT, unsigned short* __restrict__ WmuT,
    unsigned short* __restrict__ WvarT, unsigned short* __restrict__ Ktt,
    unsigned short* __restrict__ Vt)
{
    const int t = threadIdx.x;
    if (blockIdx.x < 256) {
        int idx = blockIdx.x * 256 + t;
        if (idx < 32768) {
            int n = idx & 127, k = idx >> 7;                 // k<256
            WhT[n * 256 + k] = f2bf(Wh[k * 128 + n]);
        } else if (idx < 40960) {
            int i = idx - 32768, n = i & 63, k = i >> 6;     // k<128
            WqT[n * 128 + k] = f2bf(Wq[k * 64 + n]);
        } else if (idx < 49152) {
            int i = idx - 40960, n = i & 127, k = i >> 7;    // k<64
            WoT[n * 64 + k] = f2bf(Wo[k * 128 + n]);
        } else if (idx < 57344) {
            int i = idx - 49152, n = i & 63, k = i >> 6;
            WmuT[n * 128 + k] = f2bf(Wmu[k * 64 + n]);
        } else if (idx < 65536) {
            int i = idx - 57344, n = i & 63, k = i >> 6;
            WvarT[n * 128 + k] = f2bf(Wvar[k * 64 + n]);
        }
    } else {
        int b2 = blockIdx.x - 256;           // 0..63, 2 keys per block
        __shared__ float c[2][128];
        c[t >> 7][t & 127] = cond[b2 * 256 + t];
        __syncthreads();
        int j = b2 * 2 + (t >> 7);           // key index
        int tl = t & 127;
        const float* W = (tl < 64) ? Wk : Wv;
        int col = tl & 63;
        float acc = 0.f;
#pragma unroll 8
        for (int k = 0; k < 128; ++k) acc = fmaf(c[t >> 7][k], W[k * 64 + col], acc);
        int h = col >> 5, d = col & 31;
        if (tl < 64) Ktt[((size_t)h * 128 + j) * 32 + d] = f2bf(acc * 0.17677669529663687f);
        else         Vt[((size_t)h * 32 + d) * 128 + j] = f2bf(acc);
    }
}

// ---------------- GCN1 GEMM: support1 = lrelu(ns_emb @ Wh) ------------------

__global__ __launch_bounds__(256) void gcn1_gemm(
    const float* __restrict__ A, const unsigned short* __restrict__ BT,
    unsigned short* __restrict__ C, int M)
{
    __shared__ unsigned short As[128][72];
    __shared__ unsigned short Bs[128][72];

    const int tid = threadIdx.x;
    const int lane = tid & 63, wave = tid >> 6;
    const int wm = wave & 1, wn = wave >> 1;
    const int quad = lane >> 4, l16 = lane & 15;
    const int r0 = blockIdx.x * 128;

    f32x4 acc[4][4];
#pragma unroll
    for (int mt = 0; mt < 4; ++mt)
#pragma unroll
        for (int nt = 0; nt < 4; ++nt)
#pragma unroll
            for (int r = 0; r < 4; ++r) acc[mt][nt][r] = 0.f;

    for (int kc = 0; kc < 256; kc += 64) {
#pragma unroll
        for (int i = 0; i < 8; ++i) {
            int f = tid + 256 * i;
            int row = f >> 4, kq = (f & 15) << 2;
            int gr = r0 + row;
            if (gr >= M) gr = M - 1;
            float4 v = *reinterpret_cast<const float4*>(&A[(size_t)gr * 256 + kc + kq]);
            ushort4_t pv;
            pv[0] = f2bf(v.x); pv[1] = f2bf(v.y); pv[2] = f2bf(v.z); pv[3] = f2bf(v.w);
            *reinterpret_cast<ushort4_t*>(&As[row][kq]) = pv;
        }
#pragma unroll
        for (int i = 0; i < 4; ++i) {
            int f = tid + 256 * i;
            int n = f >> 3, k8 = (f & 7) << 3;
            *reinterpret_cast<short8*>(&Bs[n][k8]) =
                *reinterpret_cast<const short8*>(&BT[(size_t)n * 256 + kc + k8]);
        }
        __syncthreads();

#pragma unroll
        for (int ks = 0; ks < 2; ++ks) {
            const int koff = ks * 32 + quad * 8;
            short8 a[4], b[4];
#pragma unroll
            for (int mt = 0; mt < 4; ++mt)
                a[mt] = *reinterpret_cast<const short8*>(&As[wm * 64 + mt * 16 + l16][koff]);
#pragma unroll
            for (int nt = 0; nt < 4; ++nt)
                b[nt] = *reinterpret_cast<const short8*>(&Bs[wn * 64 + nt * 16 + l16][koff]);
#pragma unroll
            for (int mt = 0; mt < 4; ++mt)
#pragma unroll
                for (int nt = 0; nt < 4; ++nt)
                    acc[mt][nt] = __builtin_amdgcn_mfma_f32_16x16x32_bf16(
                        a[mt], b[nt], acc[mt][nt], 0, 0, 0);
        }
        __syncthreads();
    }

#pragma unroll
    for (int mt = 0; mt < 4; ++mt)
#pragma unroll
        for (int nt = 0; nt < 4; ++nt) {
            int gc = wn * 64 + nt * 16 + l16;
#pragma unroll
            for (int r = 0; r < 4; ++r) {
                int gr = r0 + wm * 64 + mt * 16 + quad * 4 + r;
                if (gr < M) {
                    float v = acc[mt][nt][r];
                    v = v > 0.f ? v : 0.01f * v;
                    C[(size_t)gr * 128 + gc] = f2bf(v);
                }
            }
        }
}

// ---------------- fused attention + muvar kernel ----------------------------

__global__ __launch_bounds__(256) void attn_muvar_kernel(
    const unsigned short* __restrict__ hidden,  // [N,128] bf16
    const unsigned short* __restrict__ WqT,     // [64][128] bf16
    const unsigned short* __restrict__ Ktt,     // [2][128][32] bf16 (scaled)
    const unsigned short* __restrict__ Vt,      // [2][32][128] bf16
    const unsigned short* __restrict__ WoT,     // [128][64] bf16
    const unsigned short* __restrict__ WmuT,    // [64][128] bf16
    const unsigned short* __restrict__ WvarT,   // [64][128] bf16
    unsigned short* __restrict__ muvar,         // [N,128] bf16
    int M)
{
    __shared__ unsigned short Ap[128 * 136];
    __shared__ unsigned short Bp[10240];
    __shared__ unsigned short Cp[128 * 72];
    __shared__ float redm[2][128];
    __shared__ float reds[2][128];

    const int tid = threadIdx.x;
    const int lane = tid & 63, wave = tid >> 6;
    const int wm = wave & 1, wn = wave >> 1;
    const int quad = lane >> 4, l16 = lane & 15;
    const int r0 = blockIdx.x * 128;

#pragma unroll
    for (int i = 0; i < 8; ++i) {
        int f = tid + 256 * i;
        int row = f >> 4, k8 = (f & 15) << 3;
        int gr = r0 + row;
        if (gr >= M) gr = M - 1;
        *reinterpret_cast<short8*>(&Ap[row * 136 + k8]) =
            *reinterpret_cast<const short8*>(&hidden[(size_t)gr * 128 + k8]);
    }
#pragma unroll
    for (int i = 0; i < 4; ++i) {
        int f = tid + 256 * i;
        int n = f >> 4, k8 = (f & 15) << 3;
        *reinterpret_cast<short8*>(&Bp[n * 136 + k8]) =
            *reinterpret_cast<const short8*>(&WqT[(size_t)n * 128 + k8]);
    }
    __syncthreads();

    // Q = hidden @ Wq -> Cp
    {
        f32x4 accq[4][2];
#pragma unroll
        for (int mt = 0; mt < 4; ++mt)
#pragma unroll
            for (int nt = 0; nt < 2; ++nt)
#pragma unroll
                for (int r = 0; r < 4; ++r) accq[mt][nt][r] = 0.f;
#pragma unroll
        for (int ks = 0; ks < 4; ++ks) {
            const int koff = ks * 32 + quad * 8;
            short8 a[4], b[2];
#pragma unroll
            for (int mt = 0; mt < 4; ++mt)
                a[mt] = *reinterpret_cast<const short8*>(&Ap[(wm * 64 + mt * 16 + l16) * 136 + koff]);
#pragma unroll
            for (int nt = 0; nt < 2; ++nt)
                b[nt] = *reinterpret_cast<const short8*>(&Bp[(wn * 32 + nt * 16 + l16) * 136 + koff]);
#pragma unroll
            for (int mt = 0; mt < 4; ++mt)
#pragma unroll
                for (int nt = 0; nt < 2; ++nt)
                    accq[mt][nt] = __builtin_amdgcn_mfma_f32_16x16x32_bf16(
                        a[mt], b[nt], accq[mt][nt], 0, 0, 0);
        }
#pragma unroll
        for (int mt = 0; mt < 4; ++mt)
#pragma unroll
            for (int nt = 0; nt < 2; ++nt) {
                int col = wn * 32 + nt * 16 + l16;
#pragma unroll
                for (int r = 0; r < 4; ++r) {
                    int row = wm * 64 + mt * 16 + quad * 4 + r;
                    Cp[row * 72 + col] = f2bf(accq[mt][nt][r]);
                }
            }
    }
    __syncthreads();

    for (int h = 0; h < 2; ++h) {
#pragma unroll
        for (int i = 0; i < 2; ++i) {
            int f = tid + 256 * i;
            int key = f >> 2, d8 = (f & 3) << 3;
            *reinterpret_cast<short8*>(&Bp[key * 40 + d8]) =
                *reinterpret_cast<const short8*>(&Ktt[((size_t)h * 128 + key) * 32 + d8]);
        }
#pragma unroll
        for (int i = 0; i < 2; ++i) {
            int f = tid + 256 * i;
            int d = f >> 4, k8 = (f & 15) << 3;
            *reinterpret_cast<short8*>(&Bp[5120 + d * 136 + k8]) =
                *reinterpret_cast<const short8*>(&Vt[((size_t)h * 32 + d) * 128 + k8]);
        }
        __syncthreads();

        f32x4 accl[4][4];
        {
            short8 a[4], b[4];
#pragma unroll
            for (int mt = 0; mt < 4; ++mt)
                a[mt] = *reinterpret_cast<const short8*>(&Cp[(wm * 64 + mt * 16 + l16) * 72 + h * 32 + quad * 8]);
#pragma unroll
            for (int nt = 0; nt < 4; ++nt)
                b[nt] = *reinterpret_cast<const short8*>(&Bp[(wn * 64 + nt * 16 + l16) * 40 + quad * 8]);
#pragma unroll
            for (int mt = 0; mt < 4; ++mt)
#pragma unroll
                for (int nt = 0; nt < 4; ++nt) {
                    f32x4 z; z[0] = 0.f; z[1] = 0.f; z[2] = 0.f; z[3] = 0.f;
                    accl[mt][nt] = __builtin_amdgcn_mfma_f32_16x16x32_bf16(a[mt], b[nt], z, 0, 0, 0);
                }
        }

#pragma unroll
        for (int mt = 0; mt < 4; ++mt)
#pragma unroll
            for (int r = 0; r < 4; ++r) {
                float mx = fmaxf(fmaxf(accl[mt][0][r], accl[mt][1][r]),
                                 fmaxf(accl[mt][2][r], accl[mt][3][r]));
#pragma unroll
                for (int off = 1; off < 16; off <<= 1)
                    mx = fmaxf(mx, __shfl_xor(mx, off, 64));
                if (l16 == 0) redm[wn][wm * 64 + mt * 16 + quad * 4 + r] = mx;
            }
        __syncthreads();
#pragma unroll
        for (int mt = 0; mt < 4; ++mt)
#pragma unroll
            for (int r = 0; r < 4; ++r) {
                int lr = wm * 64 + mt * 16 + quad * 4 + r;
                float fm = fmaxf(redm[0][lr], redm[1][lr]);
                float s = 0.f;
#pragma unroll
                for (int nt = 0; nt < 4; ++nt) {
                    float e = __expf(accl[mt][nt][r] - fm);
                    accl[mt][nt][r] = e;
                    s += e;
                }
#pragma unroll
                for (int off = 1; off < 16; off <<= 1)
                    s += __shfl_xor(s, off, 64);
                if (l16 == 0) reds[wn][lr] = s;
            }
        __syncthreads();
#pragma unroll
        for (int mt = 0; mt < 4; ++mt)
#pragma unroll
            for (int r = 0; r < 4; ++r) {
                int lr = wm * 64 + mt * 16 + quad * 4 + r;
                float inv = 1.0f / (reds[0][lr] + reds[1][lr]);
#pragma unroll
                for (int nt = 0; nt < 4; ++nt)
                    Ap[lr * 136 + wn * 64 + nt * 16 + l16] = f2bf(accl[mt][nt][r] * inv);
            }
        __syncthreads();

        {
            f32x4 accc[4];
#pragma unroll
            for (int mt = 0; mt < 4; ++mt)
#pragma unroll
                for (int r = 0; r < 4; ++r) accc[mt][r] = 0.f;
#pragma unroll
            for (int ks = 0; ks < 4; ++ks) {
                const int koff = ks * 32 + quad * 8;
                short8 a[4];
#pragma unroll
                for (int mt = 0; mt < 4; ++mt)
                    a[mt] = *reinterpret_cast<const short8*>(&Ap[(wm * 64 + mt * 16 + l16) * 136 + koff]);
                short8 bb = *reinterpret_cast<const short8*>(&Bp[5120 + (wn * 16 + l16) * 136 + koff]);
#pragma unroll
                for (int mt = 0; mt < 4; ++mt)
                    accc[mt] = __builtin_amdgcn_mfma_f32_16x16x32_bf16(a[mt], bb, accc[mt], 0, 0, 0);
            }
#pragma unroll
            for (int mt = 0; mt < 4; ++mt)
#pragma unroll
                for (int r = 0; r < 4; ++r) {
                    int row = wm * 64 + mt * 16 + quad * 4 + r;
                    Cp[row * 72 + h * 32 + wn * 16 + l16] = f2bf(accc[mt][r]);
                }
        }
        __syncthreads();
    }

    // attended = ctx @ Wo -> Ap
#pragma unroll
    for (int i = 0; i < 4; ++i) {
        int f = tid + 256 * i;
        int n = f >> 3, k8 = (f & 7) << 3;
        *reinterpret_cast<short8*>(&Bp[n * 72 + k8]) =
            *reinterpret_cast<const short8*>(&WoT[(size_t)n * 64 + k8]);
    }
    __syncthreads();
    {
        f32x4 acca[4][4];
#pragma unroll
        for (int mt = 0; mt < 4; ++mt)
#pragma unroll
            for (int nt = 0; nt < 4; ++nt)
#pragma unroll
                for (int r = 0; r < 4; ++r) acca[mt][nt][r] = 0.f;
#pragma unroll
        for (int ks = 0; ks < 2; ++ks) {
            const int koff = ks * 32 + quad * 8;
            short8 a[4], b[4];
#pragma unroll
            for (int mt = 0; mt < 4; ++mt)
                a[mt] = *reinterpret_cast<const short8*>(&Cp[(wm * 64 + mt * 16 + l16) * 72 + koff]);
#pragma unroll
            for (int nt = 0; nt < 4; ++nt)
                b[nt] = *reinterpret_cast<const short8*>(&Bp[(wn * 64 + nt * 16 + l16) * 72 + koff]);
#pragma unroll
            for (int mt = 0; mt < 4; ++mt)
#pragma unroll
                for (int nt = 0; nt < 4; ++nt)
                    acca[mt][nt] = __builtin_amdgcn_mfma_f32_16x16x32_bf16(
                        a[mt], b[nt], acca[mt][nt], 0, 0, 0);
        }
#pragma unroll
        for (int mt = 0; mt < 4; ++mt)
#pragma unroll
            for (int nt = 0; nt < 4; ++nt) {
                int col = wn * 64 + nt * 16 + l16;
#pragma unroll
                for (int r = 0; r < 4; ++r) {
                    int row = wm * 64 + mt * 16 + quad * 4 + r;
                    Ap[row * 136 + col] = f2bf(acca[mt][nt][r]);
                }
            }
    }
    __syncthreads();

    for (int half = 0; half < 2; ++half) {
        const unsigned short* WT = half ? WvarT : WmuT;
#pragma unroll
        for (int i = 0; i < 4; ++i) {
            int f = tid + 256 * i;
            int n = f >> 4, k8 = (f & 15) << 3;
            *reinterpret_cast<short8*>(&Bp[n * 136 + k8]) =
                *reinterpret_cast<const short8*>(&WT[(size_t)n * 128 + k8]);
        }
        __syncthreads();
        f32x4 accm[4][2];
#pragma unroll
        for (int mt = 0; mt < 4; ++mt)
#pragma unroll
            for (int nt = 0; nt < 2; ++nt)
#pragma unroll
                for (int r = 0; r < 4; ++r) accm[mt][nt][r] = 0.f;
#pragma unroll
        for (int ks = 0; ks < 4; ++ks) {
            const int koff = ks * 32 + quad * 8;
            short8 a[4], b[2];
#pragma unroll
            for (int mt = 0; mt < 4; ++mt)
                a[mt] = *reinterpret_cast<const short8*>(&Ap[(wm * 64 + mt * 16 + l16) * 136 + koff]);
#pragma unroll
            for (int nt = 0; nt < 2; ++nt)
                b[nt] = *reinterpret_cast<const short8*>(&Bp[(wn * 32 + nt * 16 + l16) * 136 + koff]);
#pragma unroll
            for (int mt = 0; mt < 4; ++mt)
#pragma unroll
                for (int nt = 0; nt < 2; ++nt)
                    accm[mt][nt] = __builtin_amdgcn_mfma_f32_16x16x32_bf16(
                        a[mt], b[nt], accm[mt][nt], 0, 0, 0);
        }
#pragma unroll
        for (int mt = 0; mt < 4; ++mt)
#pragma unroll
            for (int nt = 0; nt < 2; ++nt) {
                int gc = half * 64 + wn * 32 + nt * 16 + l16;
#pragma unroll
                for (int r = 0; r < 4; ++r) {
                    int gr = r0 + wm * 64 + mt * 16 + quad * 4 + r;
                    if (gr < M) {
                        float v = accm[mt][nt][r];
                        v = v > 0.f ? v : 0.01f * v;
                        muvar[(size_t)gr * 128 + gc] = f2bf(v);
                    }
                }
            }
        __syncthreads();
    }
}

// ---------------- SpMM: one row per wave, 8-deep gather pipeline ------------
// X bf16 [N,128]; lane covers 2 features (256B full-row gather per wave).
// pack = (col, valbits), wave-uniform (scalar loads). Tail handled by one
// clamped 8-batch: idx clamped to e-1, val zeroed when OOB -> no serial tail.

template<bool SPLIT, typename OT>
__global__ __launch_bounds__(256) void spmm_kernel(
    const int* __restrict__ row_start, const int2* __restrict__ pack,
    const unsigned short* __restrict__ X,
    OT* __restrict__ out0, OT* __restrict__ out1, int N)
{
    const int wave = threadIdx.x >> 6, lane = threadIdx.x & 63;
    const int r = blockIdx.x * 4 + wave;
    if (r >= N) return;
    int s = __builtin_amdgcn_readfirstlane(row_start[r]);
    int e = __builtin_amdgcn_readfirstlane(row_start[r + 1]);
    const int fo = lane * 2;

    float ax[8], ay[8];
#pragma unroll
    for (int k = 0; k < 8; ++k) { ax[k] = 0.f; ay[k] = 0.f; }

    int i = s;
    // full 8-deep batches
    for (; i + 8 <= e; i += 8) {
        int2 p[8];
        unsigned int x[8];
#pragma unroll
        for (int k = 0; k < 8; ++k) p[k] = pack[i + k];
#pragma unroll
        for (int k = 0; k < 8; ++k)
            x[k] = *reinterpret_cast<const unsigned int*>(&X[(size_t)p[k].x * 128 + fo]);
#pragma unroll
        for (int k = 0; k < 8; ++k) {
            float v = __int_as_float(p[k].y);
            ax[k] = fmaf(v, bf2f((unsigned short)x[k]), ax[k]);
            ay[k] = fmaf(v, bf2f((unsigned short)(x[k] >> 16)), ay[k]);
        }
    }
    // clamped tail batch (at most one)
    if (i < e) {
        int2 p[8];
        unsigned int x[8];
#pragma unroll
        for (int k = 0; k < 8; ++k) {
            int idx = i + k;
            p[k] = pack[idx < e ? idx : e - 1];
        }
#pragma unroll
        for (int k = 0; k < 8; ++k)
            x[k] = *reinterpret_cast<const unsigned int*>(&X[(size_t)p[k].x * 128 + fo]);
#pragma unroll
        for (int k = 0; k < 8; ++k) {
            float v = (i + k < e) ? __int_as_float(p[k].y) : 0.f;
            ax[k] = fmaf(v, bf2f((unsigned short)x[k]), ax[k]);
            ay[k] = fmaf(v, bf2f((unsigned short)(x[k] >> 16)), ay[k]);
        }
    }

    float ox = ((ax[0] + ax[1]) + (ax[2] + ax[3])) + ((ax[4] + ax[5]) + (ax[6] + ax[7]));
    float oy = ((ay[0] + ay[1]) + (ay[2] + ay[3])) + ((ay[4] + ay[5]) + (ay[6] + ay[7]));
    ox = ox > 0.f ? ox : 0.01f * ox;
    oy = oy > 0.f ? oy : 0.01f * oy;

    if constexpr (!SPLIT) {
        unsigned int w = (unsigned int)f2bf(ox) | ((unsigned int)f2bf(oy) << 16);
        *reinterpret_cast<unsigned int*>(&out0[(size_t)r * 128 + fo]) = w;
    } else {
        if (lane < 32) {
            *reinterpret_cast<float2*>(&out0[(size_t)r * 64 + fo]) = make_float2(ox, oy);
        } else {
            *reinterpret_cast<float2*>(&out1[(size_t)r * 64 + (fo - 64)]) = make_float2(ox, oy);
        }
    }
}

// ---------------------------------------------------------------------------

extern "C" void kernel_launch(void* const* d_in, const int* in_sizes, int n_in,
                              void* d_out, int out_size, void* d_ws, size_t ws_size,
                              hipStream_t stream)
{
    const float* ns_emb   = (const float*)d_in[0];
    const int*   erows    = (const int*)d_in[1];
    const int*   ecols    = (const int*)d_in[2];
    const float* evals    = (const float*)d_in[3];
    const float* cond     = (const float*)d_in[4];
    const float* W_hidden = (const float*)d_in[5];
    const float* W_mu     = (const float*)d_in[6];
    const float* W_var    = (const float*)d_in[7];
    const float* Wq       = (const float*)d_in[8];
    const float* Wk       = (const float*)d_in[9];
    const float* Wv       = (const float*)d_in[10];
    const float* Wo       = (const float*)d_in[11];

    const int N = in_sizes[0] / 256;  // 50000
    const int E = in_sizes[1];        // 600000

    typedef unsigned short bf16;
    uint8_t* p = (uint8_t*)d_ws;
    auto alloc = [&](size_t bytes) {
        uint8_t* r = p;
        p += (bytes + 255) & ~(size_t)255;
        return r;
    };
    bf16* support1 = (bf16*)alloc(sizeof(bf16) * (size_t)N * 128);
    bf16* hidden   = (bf16*)alloc(sizeof(bf16) * (size_t)N * 128);
    bf16* muvarb   = (bf16*)alloc(sizeof(bf16) * (size_t)N * 128);
    bf16* Ktt      = (bf16*)alloc(sizeof(bf16) * 2 * 128 * 32);
    bf16* Vt       = (bf16*)alloc(sizeof(bf16) * 2 * 32 * 128);
    bf16* WhT      = (bf16*)alloc(sizeof(bf16) * 128 * 256);
    bf16* WqT      = (bf16*)alloc(sizeof(bf16) * 64 * 128);
    bf16* WoT      = (bf16*)alloc(sizeof(bf16) * 128 * 64);
    bf16* WmuT     = (bf16*)alloc(sizeof(bf16) * 64 * 128);
    bf16* WvarT    = (bf16*)alloc(sizeof(bf16) * 64 * 128);
    int*  cnt      = (int*)alloc(sizeof(int) * N);
    int*  excl     = (int*)alloc(sizeof(int) * N);
    int*  bsum     = (int*)alloc(sizeof(int) * 256);
    int*  row_start= (int*)alloc(sizeof(int) * (N + 1));
    int*  cursor   = (int*)alloc(sizeof(int) * N);
    int2* pack     = (int2*)alloc(sizeof(int2) * E);

    // ---- CSR build ----
    hipMemsetAsync(cnt, 0, sizeof(int) * N, stream);
    hist_kernel<<<(E + 255) / 256, 256, 0, stream>>>(erows, cnt, E);
    int nb = (N + 255) / 256;   // 196
    scan1_kernel<<<nb, 256, 0, stream>>>(cnt, excl, bsum, N);
    scan23_kernel<<<nb, 256, 0, stream>>>(excl, bsum, row_start, cursor, nb, N, E);
    scatter_kernel<<<(E + 255) / 256, 256, 0, stream>>>(erows, ecols, evals, cursor, pack, E);

    // ---- weight prep + K/V (merged) ----
    prep_kv_kernel<<<320, 256, 0, stream>>>(W_hidden, Wq, Wo, W_mu, W_var,
                                            cond, Wk, Wv,
                                            WhT, WqT, WoT, WmuT, WvarT, Ktt, Vt);

    const int mb = (N + 127) / 128;  // 391
    const int sblocks = (N + 3) / 4;  // 1 row per wave, 4 waves/block

    // ---- GCN1 ----
    gcn1_gemm<<<mb, 256, 0, stream>>>(ns_emb, WhT, support1, N);
    spmm_kernel<false, bf16><<<sblocks, 256, 0, stream>>>(
        row_start, pack, support1, hidden, nullptr, N);

    // ---- fused attention -> muvar ----
    attn_muvar_kernel<<<mb, 256, 0, stream>>>(hidden, WqT, Ktt, Vt, WoT,
                                              WmuT, WvarT, muvarb, N);

    // ---- final SpMM (split mu/var, fp32 out) ----
    float* out = (float*)d_out;
    spmm_kernel<true, float><<<sblocks, 256, 0, stream>>>(
        row_start, pack, muvarb, out, out + (size_t)N * 64, N);
}